// Round 2
// baseline (76086.713 us; speedup 1.0000x reference)
//
#include <hip/hip_runtime.h>

#define T_LEN 1024
#define HID   128
#define G4    512
#define BCH   4
#define NG    128      // batch groups (512 / BCH)
#define KS    64       // k-slice per WG half

__device__ __forceinline__ float fsig(float v) {
  return __builtin_amdgcn_rcpf(1.0f + __expf(-v));
}
__device__ __forceinline__ float ftanh(float v) {
  float a = fabsf(v);
  float e = __expf(-2.0f * a);
  float t = (1.0f - e) * __builtin_amdgcn_rcpf(1.0f + e);
  return copysignf(t, v);
}
__device__ __forceinline__ float gact(float v, int gt) {
  return (gt == 2) ? ftanh(v) : fsig(v);
}

__global__ void zero_flags(int* f, int n) {
  int i = blockIdx.x * 256 + threadIdx.x;
  if (i < n) f[i] = 0;
}

// ============================================================================
// Paired-WG register-persistent kernel.
// Group g = blockIdx&127 handles batches 4g..4g+3; half = blockIdx>>7 owns
// k-slice [64*half, 64*half+64) of all three weight matrices (in VGPRs) and
// state units [64*half, 64*half+64). Per step, each half computes partial
// gate pre-activations for ALL 512 rows over its k-slice; the 256 rows owned
// by the partner are exchanged through ws (agent-scope release/acquire).
// ============================================================================
__global__ void __launch_bounds__(512, 2) lstm_pair(
    const float* __restrict__ xin,
    const float* __restrict__ Wih1, const float* __restrict__ Whh1,
    const float* __restrict__ bih1, const float* __restrict__ bhh1,
    const float* __restrict__ Wih2, const float* __restrict__ Whh2,
    const float* __restrict__ bih2, const float* __restrict__ bhh2,
    const float* __restrict__ Wout, const float* __restrict__ bout,
    float* __restrict__ outp, float* __restrict__ pay, int* __restrict__ flags)
{
  __shared__ float4 h1s[KS], h2s[KS], c1s[KS], c2s[KS];
  __shared__ float4 act1g[4][64], act2g[4][64];
  __shared__ float xb[2][BCH];

  const int tid  = threadIdx.x;
  const int half = blockIdx.x >> 7;
  const int g    = blockIdx.x & (NG - 1);   // pair (g, g+128) -> same XCD (128%8==0)
  const int b0   = g * BCH;
  const int ks   = half * KS;
  const int gt   = tid >> 7;                // gate: 0:i 1:f 2:g 3:o
  const int u    = tid & (HID - 1);         // unit of this gate row
  const bool own = ((u >> 6) == half);      // do I combine/activate this row?
  const int pk   = gt * 64 + (u & 63);      // pack index in exchange buffer

  float* base        = pay + (size_t)g * 4160;
  float* ex1me       = base + half * 1040;
  const float* ex1pt = base + (half ^ 1) * 1040;
  float* ex2me       = base + 2080 + half * 1040;
  const float* ex2pt = base + 2080 + (half ^ 1) * 1040;
  int* fme1 = flags + g * 16 + half;
  int* fpt1 = flags + g * 16 + (half ^ 1);
  int* fme2 = flags + g * 16 + 2 + half;
  int* fpt2 = flags + g * 16 + 2 + (half ^ 1);

  // ---- load my weight slices into registers (one-time) ----
  float wh1[KS], wi2[KS], wh2[KS];
  {
    const float4* A4 = reinterpret_cast<const float4*>(Whh1 + (size_t)tid * HID + ks);
    const float4* B4 = reinterpret_cast<const float4*>(Wih2 + (size_t)tid * HID + ks);
    const float4* C4 = reinterpret_cast<const float4*>(Whh2 + (size_t)tid * HID + ks);
#pragma unroll
    for (int j = 0; j < KS / 4; ++j) {
      float4 v;
      v = A4[j]; wh1[4*j]=v.x; wh1[4*j+1]=v.y; wh1[4*j+2]=v.z; wh1[4*j+3]=v.w;
      v = B4[j]; wi2[4*j]=v.x; wi2[4*j+1]=v.y; wi2[4*j+2]=v.z; wi2[4*j+3]=v.w;
      v = C4[j]; wh2[4*j]=v.x; wh2[4*j+1]=v.y; wh2[4*j+2]=v.z; wh2[4*j+3]=v.w;
    }
  }
  const float bias1 = bih1[tid] + bhh1[tid];
  const float bias2 = bih2[tid] + bhh2[tid];
  const float wi1   = Wih1[tid];
  const float bo    = bout[0];
  float wo = 0.f;
  if (tid < 64) wo = Wout[half * 64 + tid];
  float poPrev = 0.f;   // my out-partial from previous step

  if (tid < KS) {
    float4 z = make_float4(0.f, 0.f, 0.f, 0.f);
    h1s[tid] = z; h2s[tid] = z; c1s[tid] = z; c2s[tid] = z;
  }
  if (tid < BCH) xb[0][tid] = xin[(size_t)(b0 + tid) * T_LEN];
  __syncthreads();

  for (int t = 0; t < T_LEN; ++t) {
    // issue next-x load early; committed to LDS in phase 4
    float xpref = 0.f;
    if (((tid & ~3) == 128) && (t + 1) < T_LEN)
      xpref = xin[(size_t)(b0 + (tid & 3)) * T_LEN + t + 1];

    // ---- phase 1: partial gates1 (W_hh1*h1) and partial W_hh2*h2, own k ----
    float a10=0.f,a11=0.f,a12=0.f,a13=0.f;
    float a20=0.f,a21=0.f,a22=0.f,a23=0.f;
#pragma unroll
    for (int k = 0; k < KS; ++k) {
      float4 h1v = h1s[k];
      float4 h2v = h2s[k];
      a10 = fmaf(wh1[k], h1v.x, a10);
      a11 = fmaf(wh1[k], h1v.y, a11);
      a12 = fmaf(wh1[k], h1v.z, a12);
      a13 = fmaf(wh1[k], h1v.w, a13);
      a20 = fmaf(wh2[k], h2v.x, a20);
      a21 = fmaf(wh2[k], h2v.y, a21);
      a22 = fmaf(wh2[k], h2v.z, a22);
      a23 = fmaf(wh2[k], h2v.w, a23);
    }
    // send gates1 partials for partner-owned rows (+ B piggybacks out-partial)
    if (!own) *reinterpret_cast<float4*>(ex1me + 4 * pk) = make_float4(a10,a11,a12,a13);
    if (half && tid < BCH) ex1me[1024 + tid] = poPrev;
    __syncthreads();   // drains all payload stores to L2 (vmcnt before barrier)
    if (tid == 0) {
      __hip_atomic_store(fme1, t + 1, __ATOMIC_RELEASE, __HIP_MEMORY_SCOPE_AGENT);
      while (__hip_atomic_load(fpt1, __ATOMIC_RELAXED, __HIP_MEMORY_SCOPE_AGENT) < t + 1)
        __builtin_amdgcn_s_sleep(2);
      (void)__hip_atomic_load(fpt1, __ATOMIC_ACQUIRE, __HIP_MEMORY_SCOPE_AGENT);
    }
    __syncthreads();
    // combine + activate my 256 rows; A also stores out(t-1)
    if (own) {
      float4 po = *reinterpret_cast<const float4*>(ex1pt + 4 * pk);
      float t0 = a10 + po.x + bias1 + wi1 * xb[t & 1][0];
      float t1 = a11 + po.y + bias1 + wi1 * xb[t & 1][1];
      float t2 = a12 + po.z + bias1 + wi1 * xb[t & 1][2];
      float t3 = a13 + po.w + bias1 + wi1 * xb[t & 1][3];
      act1g[gt][u & 63] = make_float4(gact(t0,gt), gact(t1,gt), gact(t2,gt), gact(t3,gt));
    }
    if (!half && tid < BCH && t > 0)
      outp[(size_t)(b0 + tid) * T_LEN + (t - 1)] = poPrev + ex1pt[1024 + tid] + bo;
    __syncthreads();

    // ---- phase 2: layer-1 state update for my 64 units ----
    if (tid < 64) {
      float4 iv = act1g[0][tid], fv = act1g[1][tid];
      float4 gv = act1g[2][tid], ov = act1g[3][tid];
      float4 c = c1s[tid];
      c.x = fmaf(fv.x, c.x, iv.x * gv.x);
      c.y = fmaf(fv.y, c.y, iv.y * gv.y);
      c.z = fmaf(fv.z, c.z, iv.z * gv.z);
      c.w = fmaf(fv.w, c.w, iv.w * gv.w);
      c1s[tid] = c;
      h1s[tid] = make_float4(ov.x * ftanh(c.x), ov.y * ftanh(c.y),
                             ov.z * ftanh(c.z), ov.w * ftanh(c.w));
    }
    __syncthreads();

    // ---- phase 3: a2 += W_ih2 * h1(t), own k-slice ----
#pragma unroll
    for (int k = 0; k < KS; ++k) {
      float4 hv = h1s[k];
      a20 = fmaf(wi2[k], hv.x, a20);
      a21 = fmaf(wi2[k], hv.y, a21);
      a22 = fmaf(wi2[k], hv.z, a22);
      a23 = fmaf(wi2[k], hv.w, a23);
    }
    if (!own) *reinterpret_cast<float4*>(ex2me + 4 * pk) = make_float4(a20,a21,a22,a23);
    __syncthreads();
    if (tid == 0) {
      __hip_atomic_store(fme2, t + 1, __ATOMIC_RELEASE, __HIP_MEMORY_SCOPE_AGENT);
      while (__hip_atomic_load(fpt2, __ATOMIC_RELAXED, __HIP_MEMORY_SCOPE_AGENT) < t + 1)
        __builtin_amdgcn_s_sleep(2);
      (void)__hip_atomic_load(fpt2, __ATOMIC_ACQUIRE, __HIP_MEMORY_SCOPE_AGENT);
    }
    __syncthreads();
    if (own) {
      float4 po = *reinterpret_cast<const float4*>(ex2pt + 4 * pk);
      float t0 = a20 + po.x + bias2;
      float t1 = a21 + po.y + bias2;
      float t2 = a22 + po.z + bias2;
      float t3 = a23 + po.w + bias2;
      act2g[gt][u & 63] = make_float4(gact(t0,gt), gact(t1,gt), gact(t2,gt), gact(t3,gt));
    }
    __syncthreads();

    // ---- phase 4: layer-2 state update; commit x prefetch ----
    if (tid < 64) {
      float4 iv = act2g[0][tid], fv = act2g[1][tid];
      float4 gv = act2g[2][tid], ov = act2g[3][tid];
      float4 c = c2s[tid];
      c.x = fmaf(fv.x, c.x, iv.x * gv.x);
      c.y = fmaf(fv.y, c.y, iv.y * gv.y);
      c.z = fmaf(fv.z, c.z, iv.z * gv.z);
      c.w = fmaf(fv.w, c.w, iv.w * gv.w);
      c2s[tid] = c;
      h2s[tid] = make_float4(ov.x * ftanh(c.x), ov.y * ftanh(c.y),
                             ov.z * ftanh(c.z), ov.w * ftanh(c.w));
    } else if (((tid & ~3) == 128) && (t + 1) < T_LEN) {
      xb[(t + 1) & 1][tid & 3] = xpref;
    }
    __syncthreads();

    // ---- out partial over my 64 units (wave 0) ----
    if (tid < 64) {
      float4 hv = h2s[tid];
      float p0 = wo * hv.x, p1 = wo * hv.y, p2 = wo * hv.z, p3 = wo * hv.w;
#pragma unroll
      for (int off = 1; off < 64; off <<= 1) {
        p0 += __shfl_xor(p0, off, 64);
        p1 += __shfl_xor(p1, off, 64);
        p2 += __shfl_xor(p2, off, 64);
        p3 += __shfl_xor(p3, off, 64);
      }
      if (tid < BCH) poPrev = (tid==0)?p0:(tid==1)?p1:(tid==2)?p2:p3;
    }
  }

  // ---- tail: out(T-1) ----
  if (half) {
    if (tid < BCH) ex1me[1024 + tid] = poPrev;
    __syncthreads();
    if (tid == 0)
      __hip_atomic_store(fme1, T_LEN + 1, __ATOMIC_RELEASE, __HIP_MEMORY_SCOPE_AGENT);
  } else {
    if (tid == 0) {
      while (__hip_atomic_load(fpt1, __ATOMIC_RELAXED, __HIP_MEMORY_SCOPE_AGENT) < T_LEN + 1)
        __builtin_amdgcn_s_sleep(2);
      (void)__hip_atomic_load(fpt1, __ATOMIC_ACQUIRE, __HIP_MEMORY_SCOPE_AGENT);
    }
    __syncthreads();
    if (tid < BCH)
      outp[(size_t)(b0 + tid) * T_LEN + (T_LEN - 1)] = poPrev + ex1pt[1024 + tid] + bo;
  }
}

// ============================================================================
// Fallback path (round-1 kernel, known-correct): used if ws too small or the
// cooperative launch is rejected.
// ============================================================================
__global__ void __launch_bounds__(512) transpose_w(
    const float* __restrict__ w1, const float* __restrict__ w2,
    const float* __restrict__ w3, float* __restrict__ o) {
  int m = blockIdx.y;
  const float* src = (m == 0) ? w1 : (m == 1) ? w2 : w3;
  float* dst = o + (size_t)m * G4 * HID;
  int idx = blockIdx.x * 512 + threadIdx.x;
  int j = idx >> 7;
  int k = idx & (HID - 1);
  dst[k * G4 + j] = src[idx];
}

__device__ __forceinline__ void store_out(const float4* h2buf, float wo0, float wo1,
                                          float bo, int tid, int b0,
                                          float* __restrict__ outp, int t) {
  float4 ha = h2buf[tid];
  float4 hb = h2buf[tid + 64];
  float p0 = wo0 * ha.x + wo1 * hb.x;
  float p1 = wo0 * ha.y + wo1 * hb.y;
  float p2 = wo0 * ha.z + wo1 * hb.z;
  float p3 = wo0 * ha.w + wo1 * hb.w;
#pragma unroll
  for (int off = 1; off < 64; off <<= 1) {
    p0 += __shfl_xor(p0, off, 64);
    p1 += __shfl_xor(p1, off, 64);
    p2 += __shfl_xor(p2, off, 64);
    p3 += __shfl_xor(p3, off, 64);
  }
  if (tid < BCH) {
    float v = (tid == 0) ? p0 : (tid == 1) ? p1 : (tid == 2) ? p2 : p3;
    outp[(b0 + tid) * T_LEN + t] = v + bo;
  }
}

__global__ void __launch_bounds__(512) lstm_fused(
    const float* __restrict__ xin, const float* __restrict__ Wih1,
    const float* __restrict__ bih1, const float* __restrict__ bhh1,
    const float* __restrict__ Whh1, const float* __restrict__ Wih2,
    const float* __restrict__ Whh2, int sk, int sj,
    const float* __restrict__ bih2, const float* __restrict__ bhh2,
    const float* __restrict__ Wout, const float* __restrict__ bout,
    float* __restrict__ outp) {
  __shared__ float4 h1buf[HID];
  __shared__ float4 h2buf[HID];
  __shared__ float4 g1[G4];
  __shared__ float4 g2[G4];
  __shared__ float xb[2][BCH];

  const int tid = threadIdx.x;
  const int b0 = blockIdx.x * BCH;
  const int gt = tid >> 7;

  float bias1 = bih1[tid] + bhh1[tid];
  float bias2 = bih2[tid] + bhh2[tid];
  float wi1 = Wih1[tid];
  float c1_0 = 0.f, c1_1 = 0.f, c1_2 = 0.f, c1_3 = 0.f;
  float c2_0 = 0.f, c2_1 = 0.f, c2_2 = 0.f, c2_3 = 0.f;
  float wo0 = 0.f, wo1 = 0.f, bo = 0.f;
  if (tid < 64) { wo0 = Wout[tid]; wo1 = Wout[tid + 64]; bo = bout[0]; }
  if (tid < HID) {
    h1buf[tid] = make_float4(0.f, 0.f, 0.f, 0.f);
    h2buf[tid] = make_float4(0.f, 0.f, 0.f, 0.f);
  }
  if (tid < BCH) xb[0][tid] = xin[(b0 + tid) * T_LEN];
  __syncthreads();

  const float* wp1  = Whh1 + tid * sj;
  const float* wp2  = Whh2 + tid * sj;
  const float* wpi2 = Wih2 + tid * sj;

  for (int t = 0; t < T_LEN; ++t) {
    float xpref = 0.f;
    if ((tid & ~3) == 128 && (t + 1) < T_LEN)
      xpref = xin[(b0 + (tid & 3)) * T_LEN + t + 1];

    if (tid < 64 && t > 0) store_out(h2buf, wo0, wo1, bo, tid, b0, outp, t - 1);

    float xv0 = xb[t & 1][0], xv1 = xb[t & 1][1];
    float xv2 = xb[t & 1][2], xv3 = xb[t & 1][3];
    float a10 = fmaf(wi1, xv0, bias1);
    float a11 = fmaf(wi1, xv1, bias1);
    float a12 = fmaf(wi1, xv2, bias1);
    float a13 = fmaf(wi1, xv3, bias1);
    float a20 = bias2, a21 = bias2, a22 = bias2, a23 = bias2;
#pragma unroll 8
    for (int k = 0; k < HID; ++k) {
      float w1 = wp1[k * sk];
      float w2 = wp2[k * sk];
      float4 hv1 = h1buf[k];
      float4 hv2 = h2buf[k];
      a10 = fmaf(w1, hv1.x, a10);
      a11 = fmaf(w1, hv1.y, a11);
      a12 = fmaf(w1, hv1.z, a12);
      a13 = fmaf(w1, hv1.w, a13);
      a20 = fmaf(w2, hv2.x, a20);
      a21 = fmaf(w2, hv2.y, a21);
      a22 = fmaf(w2, hv2.z, a22);
      a23 = fmaf(w2, hv2.w, a23);
    }
    float4 A1;
    A1.x = gact(a10, gt); A1.y = gact(a11, gt);
    A1.z = gact(a12, gt); A1.w = gact(a13, gt);
    g1[tid] = A1;
    __syncthreads();

    if (tid < HID) {
      float4 iv = g1[tid], fv = g1[tid + HID];
      float4 gv = g1[tid + 2 * HID], ov = g1[tid + 3 * HID];
      c1_0 = fmaf(fv.x, c1_0, iv.x * gv.x);
      c1_1 = fmaf(fv.y, c1_1, iv.y * gv.y);
      c1_2 = fmaf(fv.z, c1_2, iv.z * gv.z);
      c1_3 = fmaf(fv.w, c1_3, iv.w * gv.w);
      float4 h;
      h.x = ov.x * ftanh(c1_0);
      h.y = ov.y * ftanh(c1_1);
      h.z = ov.z * ftanh(c1_2);
      h.w = ov.w * ftanh(c1_3);
      h1buf[tid] = h;
    }
    __syncthreads();

#pragma unroll 8
    for (int k = 0; k < HID; ++k) {
      float w = wpi2[k * sk];
      float4 hv = h1buf[k];
      a20 = fmaf(w, hv.x, a20);
      a21 = fmaf(w, hv.y, a21);
      a22 = fmaf(w, hv.z, a22);
      a23 = fmaf(w, hv.w, a23);
    }
    float4 A2;
    A2.x = gact(a20, gt); A2.y = gact(a21, gt);
    A2.z = gact(a22, gt); A2.w = gact(a23, gt);
    g2[tid] = A2;
    __syncthreads();

    if (tid < HID) {
      float4 iv = g2[tid], fv = g2[tid + HID];
      float4 gv = g2[tid + 2 * HID], ov = g2[tid + 3 * HID];
      c2_0 = fmaf(fv.x, c2_0, iv.x * gv.x);
      c2_1 = fmaf(fv.y, c2_1, iv.y * gv.y);
      c2_2 = fmaf(fv.z, c2_2, iv.z * gv.z);
      c2_3 = fmaf(fv.w, c2_3, iv.w * gv.w);
      float4 h;
      h.x = ov.x * ftanh(c2_0);
      h.y = ov.y * ftanh(c2_1);
      h.z = ov.z * ftanh(c2_2);
      h.w = ov.w * ftanh(c2_3);
      h2buf[tid] = h;
    } else if ((tid & ~3) == 128 && (t + 1) < T_LEN) {
      xb[(t + 1) & 1][tid & 3] = xpref;
    }
    __syncthreads();
  }
  if (tid < 64) store_out(h2buf, wo0, wo1, bo, tid, b0, outp, T_LEN - 1);
}

extern "C" void kernel_launch(void* const* d_in, const int* in_sizes, int n_in,
                              void* d_out, int out_size, void* d_ws, size_t ws_size,
                              hipStream_t stream) {
  const float* xin  = (const float*)d_in[0];
  const float* Wih1 = (const float*)d_in[1];
  const float* Whh1 = (const float*)d_in[2];
  const float* bih1 = (const float*)d_in[3];
  const float* bhh1 = (const float*)d_in[4];
  const float* Wih2 = (const float*)d_in[5];
  const float* Whh2 = (const float*)d_in[6];
  const float* bih2 = (const float*)d_in[7];
  const float* bhh2 = (const float*)d_in[8];
  const float* Wout = (const float*)d_in[9];
  const float* bout = (const float*)d_in[10];
  float* outp = (float*)d_out;

  // ---- paired register-persistent path ----
  const size_t flagsBytes = (size_t)NG * 16 * sizeof(int);           // 8 KB
  const size_t payBytes   = (size_t)NG * 4160 * sizeof(float);       // ~2.13 MB
  if (ws_size >= flagsBytes + payBytes) {
    int*   flags = (int*)d_ws;
    float* pay   = (float*)((char*)d_ws + flagsBytes);
    zero_flags<<<(NG * 16 + 255) / 256, 256, 0, stream>>>(flags, NG * 16);
    void* args[] = { (void*)&xin,  (void*)&Wih1, (void*)&Whh1, (void*)&bih1,
                     (void*)&bhh1, (void*)&Wih2, (void*)&Whh2, (void*)&bih2,
                     (void*)&bhh2, (void*)&Wout, (void*)&bout, (void*)&outp,
                     (void*)&pay,  (void*)&flags };
    hipError_t e = hipLaunchCooperativeKernel(
        reinterpret_cast<void*>(lstm_pair), dim3(2 * NG), dim3(512), args, 0, stream);
    if (e == hipSuccess) return;
    // else fall through to the known-good fallback
  }

  // ---- fallback: round-1 kernel ----
  size_t need = (size_t)3 * G4 * HID * sizeof(float);
  if (ws_size >= need) {
    float* wt = (float*)d_ws;
    transpose_w<<<dim3(128, 3), 512, 0, stream>>>(Whh1, Wih2, Whh2, wt);
    lstm_fused<<<NG, 512, 0, stream>>>(
        xin, Wih1, bih1, bhh1,
        wt, wt + (size_t)G4 * HID, wt + (size_t)2 * G4 * HID, G4, 1,
        bih2, bhh2, Wout, bout, outp);
  } else {
    lstm_fused<<<NG, 512, 0, stream>>>(
        xin, Wih1, bih1, bhh1,
        Whh1, Wih2, Whh2, 1, HID,
        bih2, bhh2, Wout, bout, outp);
  }
}